// Round 19
// baseline (275.185 us; speedup 1.0000x reference)
//
#include <hip/hip_runtime.h>

#define TT   2048
#define CC   256
#define LL   256
#define SS   513            // 2*LL+1
#define TM   1023
#define EPSF (1e-7f)
#define LN2F (0.69314718055994531f)
#define DPTH 8              // fallback prefetch depth
#define RBTH 64
#define NCH  127
#define EMINI (-2000000000)
#define GSTR 260            // gat row stride: 256 labels + 4x blank replicas

#if __has_builtin(__builtin_amdgcn_frexp_expf)
#define FREXP_EXP __builtin_amdgcn_frexp_expf
#else
static __device__ __forceinline__ int FREXP_EXP(float x){ int e; return (frexpf(x,&e), e); }
#endif
#if __has_builtin(__builtin_amdgcn_ldexpf)
#define LDEXP __builtin_amdgcn_ldexpf
#else
#define LDEXP ldexpf
#endif

// ---------------------------------------------------------------------------
// Pass 1 (R12 verbatim, proven): compact gather.
// ---------------------------------------------------------------------------
__launch_bounds__(256, 4)
__global__ void ctc_gather_kernel(const int* __restrict__ y_true,
                                  const float* __restrict__ y_pred,
                                  float* __restrict__ gat)
{
    const int b   = blockIdx.x;
    const int i   = threadIdx.x;                 // 0..255
    const int col = y_true[b * LL + i];
    const float* rp = y_pred + (size_t)b * TT * CC;
    float*       gp = gat    + (size_t)b * TT * GSTR;
    const int tch = TT / gridDim.y;
    const int t0  = blockIdx.y * tch;
    #pragma unroll 4
    for (int t = t0; t < t0 + tch; ++t) {
        gp[(size_t)t * GSTR + i] = rp[(size_t)t * CC + col] + EPSF;
        if (i < 4)
            gp[(size_t)t * GSTR + 256 + i] = rp[(size_t)t * CC + (CC - 1)] + EPSF;
    }
}

// ---------------------------------------------------------------------------
// 13-cell window sweeps (4 own + shadow + 8 halo), trapezoid shrink by 2.
// g index k <-> cell c0-8+k (fwd) or c0+k (bwd); parity(k) == parity(cell).
// Odd cells: labels; kk[(k-1)>>1], pv[(k-1)>>1]; even cells: blank pb.
// ---------------------------------------------------------------------------
template<int NS>
__device__ __forceinline__ void fwd_swp(float (&g)[13], const float (&kk)[6],
        const float2 (&A)[4], const float2 (&B)[4], const float2 (&C)[4],
        const float (&bl)[4])
{
#define FS(K, LO) do {                                                        \
        const float pv[6] = {A[K].x,A[K].y,B[K].x,B[K].y,C[K].x,C[K].y};      \
        const float pb = bl[K];                                               \
        _Pragma("unroll")                                                     \
        for (int i = 12; i >= (LO); --i) {                                    \
            if (i & 1) g[i] = (g[i] + g[i-1] + g[i-2]*kk[(i-1)>>1])           \
                              * pv[(i-1)>>1];                                 \
            else       g[i] = (g[i] + g[i-1]) * pb;                           \
        }                                                                     \
    } while (0)
    if (NS == 4) { FS(0,2); FS(1,4); FS(2,6); FS(3,8); }
    else         { FS(0,4); FS(1,6); FS(2,8); }
#undef FS
}

template<int NS>
__device__ __forceinline__ void bwd_swp(float (&g)[13], const float (&kk)[6],
        const float2 (&A)[4], const float2 (&B)[4], const float2 (&C)[4],
        const float (&bl)[4])
{
#define BS(K, HI) do {                                                        \
        const float pv[6] = {A[K].x,A[K].y,B[K].x,B[K].y,C[K].x,C[K].y};      \
        const float pb = bl[K];                                               \
        _Pragma("unroll")                                                     \
        for (int i = 0; i <= (HI); ++i) {                                     \
            if (i & 1) g[i] = (g[i] + g[i+1] + g[i+2]*kk[(i-1)>>1])           \
                              * pv[(i-1)>>1];                                 \
            else       g[i] = (g[i] + g[i+1]) * pb;                           \
        }                                                                     \
    } while (0)
    if (NS == 4) { BS(0,10); BS(1,8); BS(2,6); BS(3,4); }
    else         { BS(0,8);  BS(1,6); BS(2,4); }
#undef BS
}

// ---------------------------------------------------------------------------
// Pass 2: 4-wave split meet-in-the-middle DP. Block = 256 threads.
//   waves 0,1: forward alpha (cells 0..255 / 256..512+shadow), rows 1..1023
//   waves 2,3: backward gamma (same cell split), rows 2046..1024
// Lane owns 4 cells (c0 = 256*sub + 4*lane) + shadow c0+4. Per 4-step group:
// halo 8 cells from lanes i-1,i-2 (shfl d1,d2) with wave-boundary values via
// double-buffered LDS slots (one barrier/group, parity-buffered -> race-free).
// ---------------------------------------------------------------------------
__launch_bounds__(256, 1)
__global__ void ctc_ms_kernel(const int* __restrict__ y_true,
                              const float* __restrict__ y_pred,
                              const float* __restrict__ gat,
                              float* __restrict__ out)
{
    __shared__ float cw[SS];
    __shared__ int   ew[128];
    __shared__ float hF[2][2][2][4];   // [buf][dir][slot][4]
    __shared__ int   hE[2][2][2];
    __shared__ float jf1s_; __shared__ int je_s_;
    __shared__ float pm[2]; __shared__ int pe[2];

    const int tid  = threadIdx.x;
    const int w    = tid >> 6;           // 0..3
    const int lane = tid & 63;
    const int dir  = (w >= 2) ? 1 : 0;   // 0 fwd, 1 bwd
    const int sub  = w & 1;              // cell-half within direction
    const int b    = blockIdx.x;
    const int blank = CC - 1;

    const int*   lab  = y_true + b * LL;
    const float* base = y_pred + (size_t)b * TT * CC;
    const float* gLb  = gat    + (size_t)b * TT * GSTR;

    const int L0 = 2 * (64 * sub + lane);          // first own label index

    float kk[6];
    #pragma unroll
    for (int m = 0; m < 6; ++m) {
        if (dir == 0) {
            const int l  = L0 - 4 + m;
            const int lc = l < 0 ? 0 : l;
            const int lp = (l - 1) < 0 ? 0 : (l - 1);
            kk[m] = (l >= 0 && (l == 0 || lab[lc] != lab[lp])) ? 1.0f : 0.0f;
        } else {
            const int l  = L0 + m;
            const int lc = l > 255 ? 255 : l;
            const int l1 = (l + 1) > 255 ? 255 : (l + 1);
            kk[m] = ((l + 1) <= 255 && lab[l1] != lab[lc]) ? 1.0f : 0.0f;
        }
    }

    float f[5];
    #pragma unroll
    for (int j = 0; j < 5; ++j) f[j] = 0.0f;
    int  e = 0;
    bool mm;
    if (dir == 0) {
        if (w == 0 && lane == 0) {
            f[0] = base[blank]  + EPSF;            // s=0, t=0
            f[1] = base[lab[0]] + EPSF;            // s=1, t=0
        }
        mm = (w == 0 && lane == 0);
    } else {
        if (w == 3 && lane == 63) {
            const float* rT = base + (size_t)(TT - 1) * CC;
            f[3] = rT[lab[255]] + EPSF;            // s=511
            f[4] = rT[blank]    + EPSF;            // s=512 (shadow, real)
        }
        mm = (w == 3 && lane == 63);
    }

    const int o0 = dir ? L0 : (L0 - 4 < 0 ? 0 : L0 - 4);
    const int o1 = dir ? (L0 + 2 > 254 ? 254 : L0 + 2) : (L0 - 2 < 0 ? 0 : L0 - 2);
    const int o2 = dir ? (L0 + 4 > 254 ? 254 : L0 + 4) : L0;
    const int bofs = 256 + (lane & 3);
    const int dstp = dir ? -GSTR : GSTR;

    float2 sA[4], sB[4], sC[4]; float sbl[4];
    const float* grow = dir ? (gLb + (size_t)2046 * GSTR)
                            : (gLb + (size_t)1 * GSTR);

#define LOADG do { const float* _rp = grow;                                   \
        _Pragma("unroll")                                                     \
        for (int k = 0; k < 4; ++k) {                                         \
            sA[k] = *(const float2*)(_rp + o0);                               \
            sB[k] = *(const float2*)(_rp + o1);                               \
            sC[k] = *(const float2*)(_rp + o2);                               \
            sbl[k] = _rp[bofs];                                               \
            _rp += dstp;                                                      \
        }                                                                     \
        grow += 4 * dstp; } while (0)

    LOADG;                                          // group 0

    // initial boundary publish (state entering group 0) -> buf 0
    if (w == 0 && lane >= 62) {
        #pragma unroll
        for (int j = 0; j < 4; ++j) hF[0][0][lane - 62][j] = f[j];
        hE[0][0][lane - 62] = e;
    }
    if (w == 3 && lane <= 1) {
        #pragma unroll
        for (int j = 0; j < 4; ++j) hF[0][1][lane][j] = f[j + 1];
        hE[0][1][lane] = e;
    }

    for (int c = 0; c < 256; ++c) {
        float2 A[4], B[4], C[4]; float bl[4];
        #pragma unroll
        for (int k = 0; k < 4; ++k) { A[k]=sA[k]; B[k]=sB[k]; C[k]=sC[k]; bl[k]=sbl[k]; }
        if (c < 255) { LOADG; }                     // group c+1
        __builtin_amdgcn_sched_barrier(0);
        __syncthreads();
        const int cbuf = c & 1, nbuf = (c + 1) & 1;

        // ---- halo exchange (8 cells from 2 neighbor lanes) ----
        float h1[4], h2[4]; int e1, e2;
        if (dir == 0) {
            #pragma unroll
            for (int j = 0; j < 4; ++j) { h1[j] = __shfl_up(f[j], 1);
                                          h2[j] = __shfl_up(f[j], 2); }
            e1 = __shfl_up(e, 1); e2 = __shfl_up(e, 2);
            if (sub == 0) {
                if (lane == 0) {
                    #pragma unroll
                    for (int j = 0; j < 4; ++j) { h1[j] = 0.0f; h2[j] = 0.0f; }
                    e1 = e; e2 = e;
                } else if (lane == 1) {
                    #pragma unroll
                    for (int j = 0; j < 4; ++j) h2[j] = 0.0f;
                    e2 = e1;
                }
            } else {
                if (lane == 0) {
                    #pragma unroll
                    for (int j = 0; j < 4; ++j) { h1[j] = hF[cbuf][0][1][j];
                                                  h2[j] = hF[cbuf][0][0][j]; }
                    e1 = hE[cbuf][0][1]; e2 = hE[cbuf][0][0];
                } else if (lane == 1) {
                    #pragma unroll
                    for (int j = 0; j < 4; ++j) h2[j] = hF[cbuf][0][1][j];
                    e2 = hE[cbuf][0][1];
                }
            }
        } else {
            #pragma unroll
            for (int j = 0; j < 4; ++j) { h1[j] = __shfl_down(f[j + 1], 1);
                                          h2[j] = __shfl_down(f[j + 1], 2); }
            e1 = __shfl_down(e, 1); e2 = __shfl_down(e, 2);
            if (sub == 1) {
                if (lane == 63) {
                    #pragma unroll
                    for (int j = 0; j < 4; ++j) { h1[j] = 0.0f; h2[j] = 0.0f; }
                    e1 = e; e2 = e;
                } else if (lane == 62) {
                    #pragma unroll
                    for (int j = 0; j < 4; ++j) h2[j] = 0.0f;
                    e2 = e1;
                }
            } else {
                if (lane == 63) {
                    #pragma unroll
                    for (int j = 0; j < 4; ++j) { h1[j] = hF[cbuf][1][0][j];
                                                  h2[j] = hF[cbuf][1][1][j]; }
                    e1 = hE[cbuf][1][0]; e2 = hE[cbuf][1][1];
                } else if (lane == 62) {
                    #pragma unroll
                    for (int j = 0; j < 4; ++j) h2[j] = hF[cbuf][1][0][j];
                    e2 = hE[cbuf][1][0];
                }
            }
        }

        // ---- align to common exponent, build window ----
        const int Eh = e1 > e2 ? e1 : e2;
        const int E  = mm ? (e > Eh ? e : Eh) : Eh;
        const int da = e1 - E, db = e2 - E, dn = e - E;
        float g[13];
        if (dir == 0) {
            #pragma unroll
            for (int j = 0; j < 4; ++j) g[j]     = LDEXP(h2[j], db);
            #pragma unroll
            for (int j = 0; j < 4; ++j) g[4 + j] = LDEXP(h1[j], da);
            #pragma unroll
            for (int j = 0; j < 5; ++j) g[8 + j] = LDEXP(f[j], dn);
        } else {
            #pragma unroll
            for (int j = 0; j < 5; ++j) g[j]     = LDEXP(f[j], dn);
            #pragma unroll
            for (int j = 0; j < 4; ++j) g[5 + j] = LDEXP(h1[j], da);
            #pragma unroll
            for (int j = 0; j < 4; ++j) g[9 + j] = LDEXP(h2[j], db);
        }
        e = E;

        // ---- sweeps ----
        if (c < 255) {
            if (dir == 0) fwd_swp<4>(g, kk, A, B, C, bl);
            else          bwd_swp<4>(g, kk, A, B, C, bl);
        } else {
            if (dir == 0) fwd_swp<3>(g, kk, A, B, C, bl);
            else          bwd_swp<3>(g, kk, A, B, C, bl);
        }

        // ---- writeback + renorm ----
        if (dir == 0) {
            #pragma unroll
            for (int j = 0; j < 5; ++j) f[j] = g[8 + j];
        } else {
            #pragma unroll
            for (int j = 0; j < 5; ++j) f[j] = g[j];
        }
        float mx = f[0];
        #pragma unroll
        for (int j = 1; j < 5; ++j) mx = fmaxf(mx, f[j]);
        const int em = FREXP_EXP(mx);
        #pragma unroll
        for (int j = 0; j < 5; ++j) f[j] = LDEXP(f[j], -em);
        e += em;
        mm = (mx > 0.0f);

        // ---- publish boundary for next group ----
        if (c < 255) {
            if (w == 0 && lane >= 62) {
                #pragma unroll
                for (int j = 0; j < 4; ++j) hF[nbuf][0][lane - 62][j] = f[j];
                hE[nbuf][0][lane - 62] = e;
            }
            if (w == 3 && lane <= 1) {
                #pragma unroll
                for (int j = 0; j < 4; ++j) hF[nbuf][1][lane][j] = f[j + 1];
                hE[nbuf][1][lane] = e;
            }
        }
    }
#undef LOADG

    // ---- combo (bwd): beta[TM][s] = g[s]+g[s+1]+allow2[s+2]*g[s+2] ----
    if (w == 3 && lane == 0) { jf1s_ = f[1]; je_s_ = e; }
    __syncthreads();

    if (dir == 1) {
        float d1 = __shfl_down(f[1], 1);
        int   de = __shfl_down(e, 1);
        if (sub == 0 && lane == 63) { d1 = jf1s_; de = je_s_; }
        if (sub == 1 && lane == 63) { d1 = 0.0f; de = e; }
        int dlt = de - e;
        if (dlt >= RBTH) {
            #pragma unroll
            for (int j = 0; j < 5; ++j) f[j] = LDEXP(f[j], -dlt);
            e = de; dlt = 0;
        }
        const float bf = LDEXP(d1, dlt);
        const int c0 = 4 * (64 * sub + lane);
        cw[c0 + 0] = f[0] + f[1];
        cw[c0 + 1] = f[1] + f[2] + f[3] * kk[0];
        cw[c0 + 2] = f[2] + f[3];
        cw[c0 + 3] = f[3] + f[4] + bf * kk[1];
        if (sub == 1 && lane == 63) cw[512] = f[4];
        ew[sub * 64 + lane] = e;
    }
    __syncthreads();

    // ---- join (fwd): per-lane dot, 2-stage reduction ----
    if (dir == 0) {
        const int c0 = 4 * (64 * sub + lane);
        float part = f[0]*cw[c0] + f[1]*cw[c0+1] + f[2]*cw[c0+2] + f[3]*cw[c0+3];
        if (sub == 1 && lane == 63) part += f[4] * cw[512];
        int   ep = (part > 0.0f) ? (e + ew[sub * 64 + lane]) : EMINI;
        float m  = part;
        #pragma unroll
        for (int d = 1; d < 64; d <<= 1) {
            const float mo = __shfl_xor(m, d);
            const int   eo = __shfl_xor(ep, d);
            const int   E2 = ep > eo ? ep : eo;
            m  = LDEXP(m, ep - E2) + LDEXP(mo, eo - E2);
            ep = E2;
        }
        if (lane == 0) { pm[sub] = m; pe[sub] = ep; }
    }
    __syncthreads();
    if (tid == 0) {
        const float m0 = pm[0], m1 = pm[1];
        const int   p0 = pe[0], p1 = pe[1];
        const int   E2 = p0 > p1 ? p0 : p1;
        const float m  = LDEXP(m0, p0 - E2) + LDEXP(m1, p1 - E2);
        out[b] = -LN2F * ((float)E2 + __builtin_amdgcn_logf(m));
    }
}

// ---------------------------------------------------------------------------
// Fallback (round-6 verbatim, proven): used only if ws_size is too small.
// ---------------------------------------------------------------------------
__launch_bounds__(128, 1)
__global__ void ctc_fb_kernel(const int* __restrict__ y_true,
                              const float* __restrict__ y_pred,
                              float* __restrict__ out)
{
    __shared__ float cw[SS];
    __shared__ int   ew[64];

    const int tid   = threadIdx.x;
    const int w     = tid >> 6;
    const int lane  = tid & 63;
    const int b     = blockIdx.x;
    const int blank = CC - 1;

    const int*   lab  = y_true + b * LL;
    const float* base = y_pred + (size_t)b * TT * CC;

    int   col[4];
    float kup[4], kdn[4];
    #pragma unroll
    for (int i = 0; i < 4; ++i) {
        const int li = 4 * lane + i;
        const int z  = lab[li];
        col[i] = z;
        const int zm = (li >= 1) ? lab[li - 1] : -1;
        kup[i] = (z != zm) ? 1.0f : 0.0f;
        kdn[i] = (li <= 254 && lab[li + 1] != z) ? 1.0f : 0.0f;
    }

    float f[9];
    #pragma unroll
    for (int j = 0; j < 9; ++j) f[j] = 0.0f;
    int  e = 0;
    bool lzero;

    if (w == 0) {
        if (lane == 0) { f[0] = base[blank] + EPSF; f[1] = base[col[0]] + EPSF; }
        lzero = (lane != 0);
    } else {
        if (lane == 63) {
            const float* rT = base + (size_t)(TT - 1) * CC;
            f[7] = rT[col[3]] + EPSF; f[8] = rT[blank] + EPSF;
        }
        lzero = (lane != 63);
    }

    float pfb[DPTH]; float pfl[DPTH][4];
    #pragma unroll
    for (int k = 0; k < DPTH; ++k) {
        const int r = (w == 0) ? (1 + k) : (TT - 2 - k);
        const float* rp = base + (size_t)r * CC;
        pfb[k] = rp[blank];
        #pragma unroll
        for (int i = 0; i < 4; ++i) pfl[k][i] = rp[col[i]];
    }

    auto renorm = [&]() {
        float m = fmaxf(fmaxf(fmaxf(f[0], f[1]), fmaxf(f[2], f[3])),
                        fmaxf(fmaxf(f[4], f[5]), fmaxf(f[6], fmaxf(f[7], f[8]))));
        const int em = FREXP_EXP(m);
        #pragma unroll
        for (int j = 0; j < 9; ++j) f[j] = LDEXP(f[j], -em);
        e += em;
    };
    auto fwd_step = [&](float pb, float p0, float p1, float p2, float p3) {
        float u7 = __shfl_up(f[7], 1);
        int   ue = __shfl_up(e, 1);
        if (lane == 0) { u7 = 0.0f; ue = e; }
        int dlt = ue - e;
        const bool rb = lzero || (dlt >= RBTH);
        if (__ballot(rb)) {
            const int sh = rb ? -dlt : 0;
            #pragma unroll
            for (int j = 0; j < 9; ++j) f[j] = LDEXP(f[j], sh);
            e = rb ? ue : e; dlt = rb ? 0 : dlt;
            lzero = lzero && (u7 == 0.0f);
        }
        const float bf = LDEXP(u7, dlt);
        const float n0 = (f[0] + bf) * pb;
        const float n1 = (f[1] + f[0] + bf   * kup[0]) * p0;
        const float n2 = (f[2] + f[1]) * pb;
        const float n3 = (f[3] + f[2] + f[1] * kup[1]) * p1;
        const float n4 = (f[4] + f[3]) * pb;
        const float n5 = (f[5] + f[4] + f[3] * kup[2]) * p2;
        const float n6 = (f[6] + f[5]) * pb;
        const float n7 = (f[7] + f[6] + f[5] * kup[3]) * p3;
        const float n8 = (f[8] + f[7]) * pb;
        f[0]=n0; f[1]=n1; f[2]=n2; f[3]=n3; f[4]=n4;
        f[5]=n5; f[6]=n6; f[7]=n7; f[8]=n8;
    };
    auto bwd_step = [&](float pb, float p0, float p1, float p2, float p3) {
        float d1 = __shfl_down(f[1], 1);
        int   de = __shfl_down(e, 1);
        if (lane == 63) { d1 = 0.0f; de = e; }
        int dlt = de - e;
        const bool rb = lzero || (dlt >= RBTH);
        if (__ballot(rb)) {
            const int sh = rb ? -dlt : 0;
            #pragma unroll
            for (int j = 0; j < 9; ++j) f[j] = LDEXP(f[j], sh);
            e = rb ? de : e; dlt = rb ? 0 : dlt;
            lzero = lzero && (d1 == 0.0f);
        }
        const float bf = LDEXP(d1, dlt);
        const float n0 = (f[0] + f[1]) * pb;
        const float n1 = (f[1] + f[2] + f[3] * kdn[0]) * p0;
        const float n2 = (f[2] + f[3]) * pb;
        const float n3 = (f[3] + f[4] + f[5] * kdn[1]) * p1;
        const float n4 = (f[4] + f[5]) * pb;
        const float n5 = (f[5] + f[6] + f[7] * kdn[2]) * p2;
        const float n6 = (f[6] + f[7]) * pb;
        const float n7 = (f[7] + f[8] + bf   * kdn[3]) * p3;
        const float n8 = (f[8] + bf) * pb;
        f[0]=n0; f[1]=n1; f[2]=n2; f[3]=n3; f[4]=n4;
        f[5]=n5; f[6]=n6; f[7]=n7; f[8]=n8;
    };

    if (w == 0) {
        for (int c = 0; c < NCH; ++c) {
            #pragma unroll
            for (int k = 0; k < DPTH; ++k) {
                const float pb = pfb[k] + EPSF;
                const float p0 = pfl[k][0] + EPSF, p1 = pfl[k][1] + EPSF;
                const float p2 = pfl[k][2] + EPSF, p3 = pfl[k][3] + EPSF;
                int tp = 1 + c * DPTH + k + DPTH; if (tp > TM) tp = TM;
                const float* rp = base + (size_t)tp * CC;
                pfb[k] = rp[blank];
                #pragma unroll
                for (int i = 0; i < 4; ++i) pfl[k][i] = rp[col[i]];
                fwd_step(pb, p0, p1, p2, p3);
                if (k == 3 || k == 7) renorm();
            }
        }
        #pragma unroll
        for (int k = 0; k < 7; ++k) {
            fwd_step(pfb[k] + EPSF, pfl[k][0] + EPSF, pfl[k][1] + EPSF,
                     pfl[k][2] + EPSF, pfl[k][3] + EPSF);
            if (k == 3) renorm();
        }
    } else {
        for (int c = 0; c < NCH; ++c) {
            #pragma unroll
            for (int k = 0; k < DPTH; ++k) {
                const float pb = pfb[k] + EPSF;
                const float p0 = pfl[k][0] + EPSF, p1 = pfl[k][1] + EPSF;
                const float p2 = pfl[k][2] + EPSF, p3 = pfl[k][3] + EPSF;
                int tp = (TT - 2) - (c * DPTH + k) - DPTH; if (tp < TM + 1) tp = TM + 1;
                const float* rp = base + (size_t)tp * CC;
                pfb[k] = rp[blank];
                #pragma unroll
                for (int i = 0; i < 4; ++i) pfl[k][i] = rp[col[i]];
                bwd_step(pb, p0, p1, p2, p3);
                if (k == 3 || k == 7) renorm();
            }
        }
        #pragma unroll
        for (int k = 0; k < 7; ++k) {
            bwd_step(pfb[k] + EPSF, pfl[k][0] + EPSF, pfl[k][1] + EPSF,
                     pfl[k][2] + EPSF, pfl[k][3] + EPSF);
            if (k == 3) renorm();
        }

        float d1 = __shfl_down(f[1], 1);
        int   de = __shfl_down(e, 1);
        if (lane == 63) { d1 = 0.0f; de = e; }
        int dlt = de - e;
        if (dlt >= RBTH) {
            #pragma unroll
            for (int j = 0; j < 9; ++j) f[j] = LDEXP(f[j], -dlt);
            e = de; dlt = 0;
        }
        const float bf = LDEXP(d1, dlt);
        float cb[9];
        cb[0] = f[0] + f[1];
        cb[1] = f[1] + f[2] + f[3] * kdn[0];
        cb[2] = f[2] + f[3];
        cb[3] = f[3] + f[4] + f[5] * kdn[1];
        cb[4] = f[4] + f[5];
        cb[5] = f[5] + f[6] + f[7] * kdn[2];
        cb[6] = f[6] + f[7];
        cb[7] = f[7] + f[8] + bf   * kdn[3];
        cb[8] = f[8] + bf;
        #pragma unroll
        for (int j = 0; j < 8; ++j) cw[8 * lane + j] = cb[j];
        if (lane == 63) cw[512] = cb[8];
        ew[lane] = e;
    }

    __syncthreads();

    if (w == 0) {
        float part = 0.0f;
        #pragma unroll
        for (int j = 0; j < 8; ++j) part += f[j] * cw[8 * lane + j];
        if (lane == 63) part += f[8] * cw[512];
        int   ep = (part > 0.0f) ? (e + ew[lane]) : EMINI;
        float m  = part;
        #pragma unroll
        for (int d = 1; d < 64; d <<= 1) {
            const float mo = __shfl_xor(m, d);
            const int   eo = __shfl_xor(ep, d);
            const int   E  = ep > eo ? ep : eo;
            m  = LDEXP(m, ep - E) + LDEXP(mo, eo - E);
            ep = E;
        }
        if (lane == 0)
            out[b] = -LN2F * ((float)ep + __builtin_amdgcn_logf(m));
    }
}

extern "C" void kernel_launch(void* const* d_in, const int* in_sizes, int n_in,
                              void* d_out, int out_size, void* d_ws, size_t ws_size,
                              hipStream_t stream)
{
    const int*   y_true = (const int*)d_in[0];
    const float* y_pred = (const float*)d_in[1];
    float*       out    = (float*)d_out;
    const int B = in_sizes[0] / LL;   // 32

    const size_t need = (size_t)B * TT * GSTR * sizeof(float);  // ~68.2 MB
    if (ws_size >= need) {
        float* gat = (float*)d_ws;
        ctc_gather_kernel<<<dim3(B, 32), 256, 0, stream>>>(y_true, y_pred, gat);
        ctc_ms_kernel<<<B, 256, 0, stream>>>(y_true, y_pred, gat, out);
    } else {
        ctc_fb_kernel<<<B, 128, 0, stream>>>(y_true, y_pred, out);
    }
}

// Round 20
// 175.272 us; speedup vs baseline: 1.5700x; 1.5700x over previous
//
#include <hip/hip_runtime.h>

#define TT   2048
#define CC   256
#define LL   256
#define SS   513            // 2*LL+1
#define TM   1023
#define EPSF (1e-7f)
#define LN2F (0.69314718055994531f)
#define DPTH 8              // fallback prefetch depth
#define RBTH 64
#define NCH  127
#define EMINI (-2000000000)
#define GSTR 260            // gat row stride: 256 labels + 4x blank replicas

#if __has_builtin(__builtin_amdgcn_frexp_expf)
#define FREXP_EXP __builtin_amdgcn_frexp_expf
#else
static __device__ __forceinline__ int FREXP_EXP(float x){ int e; return (frexpf(x,&e), e); }
#endif
#if __has_builtin(__builtin_amdgcn_ldexpf)
#define LDEXP __builtin_amdgcn_ldexpf
#else
#define LDEXP ldexpf
#endif

// ---------------------------------------------------------------------------
// Pass 1 (R12 verbatim, proven): compact gather.
//   gat[b][t][i]     = y_pred[b][t][lab[i]] + eps   (i = 0..255)
//   gat[b][t][256+j] = y_pred[b][t][blank]  + eps   (j = 0..3, replicas)
// ---------------------------------------------------------------------------
__launch_bounds__(256, 4)
__global__ void ctc_gather_kernel(const int* __restrict__ y_true,
                                  const float* __restrict__ y_pred,
                                  float* __restrict__ gat)
{
    const int b   = blockIdx.x;
    const int i   = threadIdx.x;                 // 0..255
    const int col = y_true[b * LL + i];
    const float* rp = y_pred + (size_t)b * TT * CC;
    float*       gp = gat    + (size_t)b * TT * GSTR;
    const int tch = TT / gridDim.y;
    const int t0  = blockIdx.y * tch;
    #pragma unroll 4
    for (int t = t0; t < t0 + tch; ++t) {
        gp[(size_t)t * GSTR + i] = rp[(size_t)t * CC + col] + EPSF;
        if (i < 4)
            gp[(size_t)t * GSTR + 256 + i] = rp[(size_t)t * CC + (CC - 1)] + EPSF;
    }
}

// ---------------------------------------------------------------------------
// Grouped DP step engines (R8-verified math, register pv).
// Window g[17]: fwd g[0..7]=prev-lane halo, g[8..16]=own f[0..8];
//              bwd g[0..8]=own, g[9..16]=next-lane halo.
// pv[8] per sweep: fwd {prev4, own4}, bwd {own4, next4}; blank separate.
// ---------------------------------------------------------------------------
template<int NSTEP>
__device__ __forceinline__ void fwd_group(float (&f)[9], int &e, bool &mm,
        const float (&kk)[8], int lane,
        float4 o0, float4 o1, float4 o2, float4 o3,
        float4 q0, float4 q1, float4 q2, float4 q3,
        float b0, float b1, float b2, float b3)
{
    float h[8];
    #pragma unroll
    for (int j = 0; j < 8; ++j) h[j] = __shfl_up(f[j], 1);
    int he = __shfl_up(e, 1);
    if (lane == 0) {
        he = e;
        #pragma unroll
        for (int j = 0; j < 8; ++j) h[j] = 0.0f;
    }
    const int E  = mm ? (e > he ? e : he) : he;
    const int dh = he - E, dn = e - E;
    float g[17];
    #pragma unroll
    for (int j = 0; j < 8; ++j) g[j] = LDEXP(h[j], dh);
    #pragma unroll
    for (int j = 0; j < 9; ++j) g[8 + j] = LDEXP(f[j], dn);
    e = E;

#define FSW(Q, O, B, LO) do {                                                 \
        const float pv[8] = {Q.x,Q.y,Q.z,Q.w,O.x,O.y,O.z,O.w};                \
        _Pragma("unroll")                                                     \
        for (int i = 16; i >= (LO); --i) {                                    \
            if (i & 1) g[i] = (g[i] + g[i-1] + g[i-2]*kk[(i-1)>>1])           \
                              * pv[(i-1)>>1];                                 \
            else       g[i] = (g[i] + g[i-1]) * (B);                          \
        }                                                                     \
    } while (0)

    if (NSTEP == 4) {
        FSW(q0,o0,b0,2); FSW(q1,o1,b1,4); FSW(q2,o2,b2,6); FSW(q3,o3,b3,8);
    } else {
        FSW(q0,o0,b0,4); FSW(q1,o1,b1,6); FSW(q2,o2,b2,8);
    }
#undef FSW

    #pragma unroll
    for (int j = 0; j < 9; ++j) f[j] = g[8 + j];
    float mx = f[0];
    #pragma unroll
    for (int j = 1; j < 9; ++j) mx = fmaxf(mx, f[j]);
    const int em = FREXP_EXP(mx);
    #pragma unroll
    for (int j = 0; j < 9; ++j) f[j] = LDEXP(f[j], -em);
    e += em;
    mm = (mx > 0.0f);
}

template<int NSTEP>
__device__ __forceinline__ void bwd_group(float (&f)[9], int &e, bool &mm,
        const float (&kk)[8], int lane,
        float4 o0, float4 o1, float4 o2, float4 o3,
        float4 q0, float4 q1, float4 q2, float4 q3,
        float b0, float b1, float b2, float b3)
{
    float h[8];
    #pragma unroll
    for (int j = 0; j < 8; ++j) h[j] = __shfl_down(f[j + 1], 1);
    int he = __shfl_down(e, 1);
    if (lane == 63) {
        he = e;
        #pragma unroll
        for (int j = 0; j < 8; ++j) h[j] = 0.0f;
    }
    const int E  = mm ? (e > he ? e : he) : he;
    const int dh = he - E, dn = e - E;
    float g[17];
    #pragma unroll
    for (int j = 0; j < 9; ++j) g[j] = LDEXP(f[j], dn);
    #pragma unroll
    for (int j = 0; j < 8; ++j) g[9 + j] = LDEXP(h[j], dh);
    e = E;

#define BSW(O, Q, B, HI) do {                                                 \
        const float pv[8] = {O.x,O.y,O.z,O.w,Q.x,Q.y,Q.z,Q.w};                \
        _Pragma("unroll")                                                     \
        for (int i = 0; i <= (HI); ++i) {                                     \
            if (i & 1) g[i] = (g[i] + g[i+1] + g[i+2]*kk[(i-1)>>1])           \
                              * pv[(i-1)>>1];                                 \
            else       g[i] = (g[i] + g[i+1]) * (B);                          \
        }                                                                     \
    } while (0)

    if (NSTEP == 4) {
        BSW(o0,q0,b0,14); BSW(o1,q1,b1,12); BSW(o2,q2,b2,10); BSW(o3,q3,b3,8);
    } else {
        BSW(o0,q0,b0,12); BSW(o1,q1,b1,10); BSW(o2,q2,b2,8);
    }
#undef BSW

    #pragma unroll
    for (int j = 0; j < 9; ++j) f[j] = g[j];
    float mx = f[0];
    #pragma unroll
    for (int j = 1; j < 9; ++j) mx = fmaxf(mx, f[j]);
    const int em = FREXP_EXP(mx);
    #pragma unroll
    for (int j = 0; j < 9; ++j) f[j] = LDEXP(f[j], -em);
    e += em;
    mm = (mx > 0.0f);
}

// ---------------------------------------------------------------------------
// Pass 2: grouped meet-in-the-middle DP. Block = 128 threads (2 waves).
//   wave 0: forward alpha, rows 1..TM; wave 1: backward gamma, rows 2046..1024.
// 255 full groups of 4 steps + 3-step tail = 1023 steps/wave. Per group:
// one batched 9-shfl exchange, 12 coalesced VMEM loads (2 float4 + blank
// per step), 4 lane-local 17-cell sweeps, one renorm. Double-buffered
// group slots -> ~2 groups of VM slack. Main-loop lgkm = shfls only.
// ---------------------------------------------------------------------------
__launch_bounds__(128, 1)
__global__ void ctc_grp_kernel(const int* __restrict__ y_true,
                               const float* __restrict__ y_pred,
                               const float* __restrict__ gat,
                               float* __restrict__ out)
{
    __shared__ float cw[SS];
    __shared__ int   ew[64];

    const int tid   = threadIdx.x;
    const int w     = tid >> 6;          // 0 = fwd, 1 = bwd
    const int lane  = tid & 63;
    const int b     = blockIdx.x;
    const int blank = CC - 1;

    const int*   lab  = y_true + b * LL;
    const float* base = y_pred + (size_t)b * TT * CC;
    const float* gLb  = gat    + (size_t)b * TT * GSTR;

    // kk[8]: fwd = allow2 into window cells (labels 4l-4..4l+3);
    //        bwd = allow2 out of window cells (labels 4l..4l+7)
    float kk[8];
    if (w == 0) {
        #pragma unroll
        for (int j = 0; j < 8; ++j) {
            const int li  = 4 * lane - 4 + j;
            const int lic = li < 0 ? 0 : li;
            const int z   = lab[lic];
            const int zm  = (li >= 1) ? lab[li - 1] : -1;
            kk[j] = (li >= 0 && z != zm) ? 1.0f : 0.0f;
        }
    } else {
        #pragma unroll
        for (int j = 0; j < 8; ++j) {
            const int li  = 4 * lane + j;
            const int lic = li > 255 ? 255 : li;
            const int z   = lab[lic];
            kk[j] = (li <= 254 && lab[li + 1] != z) ? 1.0f : 0.0f;
        }
    }

    float f[9];
    #pragma unroll
    for (int j = 0; j < 9; ++j) f[j] = 0.0f;
    int  e = 0;
    bool mm;

    if (w == 0) {
        if (lane == 0) {
            f[0] = base[blank]        + EPSF;      // s=0, t=0
            f[1] = base[lab[0]]       + EPSF;      // s=1, t=0
        }
        mm = (lane == 0);
    } else {
        if (lane == 63) {
            const float* rT = base + (size_t)(TT - 1) * CC;
            f[7] = rT[lab[255]] + EPSF;            // s=511, t=TT-1
            f[8] = rT[blank]    + EPSF;            // s=512 (shadow), t=TT-1
        }
        mm = (lane == 63);
    }

    // ---- group-slot registers ----
    const int oofs = 4 * lane;
    const int qofs = (w == 0) ? (4 * lane - 4 < 0 ? 0 : 4 * lane - 4)
                              : (4 * lane + 4);
    const int bofs = 256 + (lane & 3);
    const int dstp = (w == 0) ? GSTR : -GSTR;

    float4 s0o[4], s0q[4]; float s0b[4];
    float4 s1o[4], s1q[4]; float s1b[4];

#define LOADG(SO, SQ, SB, ROWP) do {                                          \
        const float* _rp = (ROWP);                                            \
        _Pragma("unroll")                                                     \
        for (int k = 0; k < 4; ++k) {                                         \
            SO[k] = *(const float4*)(_rp + oofs);                             \
            SQ[k] = *(const float4*)(_rp + qofs);                             \
            SB[k] = _rp[bofs];                                                \
            _rp += dstp;                                                      \
        }                                                                     \
    } while (0)

    // prologue: groups 0 and 1
    const float* grow = (w == 0) ? (gLb + (size_t)1 * GSTR)
                                 : (gLb + (size_t)2046 * GSTR);
    LOADG(s0o, s0q, s0b, grow); grow += 4 * dstp;
    LOADG(s1o, s1q, s1b, grow); grow += 4 * dstp;

#define PROC(SO, SQ, SB, NS) do {                                             \
        const float4 a0 = SO[0], a1 = SO[1], a2 = SO[2], a3 = SO[3];          \
        const float4 p0 = SQ[0], p1 = SQ[1], p2 = SQ[2], p3 = SQ[3];          \
        const float  c0 = SB[0], c1 = SB[1], c2 = SB[2], c3 = SB[3];          \
        if (NS == 4) { LOADG(SO, SQ, SB, grow); grow += 4 * dstp; }           \
        __builtin_amdgcn_sched_barrier(0);                                    \
        if (w == 0) fwd_group<NS>(f, e, mm, kk, lane,                         \
                        a0,a1,a2,a3, p0,p1,p2,p3, c0,c1,c2,c3);               \
        else        bwd_group<NS>(f, e, mm, kk, lane,                         \
                        a0,a1,a2,a3, p0,p1,p2,p3, c0,c1,c2,c3);               \
    } while (0)

    // main loop: 127 iterations x 2 groups = groups 0..253
    for (int c = 0; c < 127; ++c) {
        PROC(s0o, s0q, s0b, 4);        // group 2c;   reload <- group 2c+2
        PROC(s1o, s1q, s1b, 4);        // group 2c+1; reload <- group 2c+3
    }
    // epilogue: group 254 (full)
    {
        const float4 a0 = s0o[0], a1 = s0o[1], a2 = s0o[2], a3 = s0o[3];
        const float4 p0 = s0q[0], p1 = s0q[1], p2 = s0q[2], p3 = s0q[3];
        const float  c0 = s0b[0], c1 = s0b[1], c2 = s0b[2], c3 = s0b[3];
        if (w == 0) fwd_group<4>(f, e, mm, kk, lane,
                        a0,a1,a2,a3, p0,p1,p2,p3, c0,c1,c2,c3);
        else        bwd_group<4>(f, e, mm, kk, lane,
                        a0,a1,a2,a3, p0,p1,p2,p3, c0,c1,c2,c3);
    }
    {   // tail: group 255, 3 steps
        const float4 a0 = s1o[0], a1 = s1o[1], a2 = s1o[2], a3 = s1o[3];
        const float4 p0 = s1q[0], p1 = s1q[1], p2 = s1q[2], p3 = s1q[3];
        const float  c0 = s1b[0], c1 = s1b[1], c2 = s1b[2], c3 = s1b[3];
        if (w == 0) fwd_group<3>(f, e, mm, kk, lane,
                        a0,a1,a2,a3, p0,p1,p2,p3, c0,c1,c2,c3);
        else        bwd_group<3>(f, e, mm, kk, lane,
                        a0,a1,a2,a3, p0,p1,p2,p3, c0,c1,c2,c3);
    }
#undef PROC
#undef LOADG

    if (w == 1) {
        // combo: beta[TM][s] = g[s] + g[s+1] + allow2[s+2]*g[s+2]
        float d1 = __shfl_down(f[1], 1);
        int   de = __shfl_down(e, 1);
        if (lane == 63) { d1 = 0.0f; de = e; }
        int dlt = de - e;
        if (dlt >= RBTH) {
            #pragma unroll
            for (int j = 0; j < 9; ++j) f[j] = LDEXP(f[j], -dlt);
            e = de; dlt = 0;
        }
        const float bf = LDEXP(d1, dlt);
        float cb[9];
        cb[0] = f[0] + f[1];
        cb[1] = f[1] + f[2] + f[3] * kk[0];
        cb[2] = f[2] + f[3];
        cb[3] = f[3] + f[4] + f[5] * kk[1];
        cb[4] = f[4] + f[5];
        cb[5] = f[5] + f[6] + f[7] * kk[2];
        cb[6] = f[6] + f[7];
        cb[7] = f[7] + f[8] + bf   * kk[3];
        cb[8] = f[8] + bf;                          // combo[512]
        #pragma unroll
        for (int j = 0; j < 8; ++j) cw[8 * lane + j] = cb[j];
        if (lane == 63) cw[512] = cb[8];
        ew[lane] = e;
    }

    __syncthreads();

    if (w == 0) {
        float part = 0.0f;
        #pragma unroll
        for (int j = 0; j < 8; ++j) part += f[j] * cw[8 * lane + j];
        if (lane == 63) part += f[8] * cw[512];
        int   ep = (part > 0.0f) ? (e + ew[lane]) : EMINI;
        float m  = part;
        #pragma unroll
        for (int d = 1; d < 64; d <<= 1) {
            const float mo = __shfl_xor(m, d);
            const int   eo = __shfl_xor(ep, d);
            const int   E  = ep > eo ? ep : eo;
            m  = LDEXP(m, ep - E) + LDEXP(mo, eo - E);
            ep = E;
        }
        if (lane == 0)
            out[b] = -LN2F * ((float)ep + __builtin_amdgcn_logf(m));
    }
}

// ---------------------------------------------------------------------------
// Fallback (round-6 verbatim, proven): used only if ws_size is too small.
// ---------------------------------------------------------------------------
__launch_bounds__(128, 1)
__global__ void ctc_fb_kernel(const int* __restrict__ y_true,
                              const float* __restrict__ y_pred,
                              float* __restrict__ out)
{
    __shared__ float cw[SS];
    __shared__ int   ew[64];

    const int tid   = threadIdx.x;
    const int w     = tid >> 6;
    const int lane  = tid & 63;
    const int b     = blockIdx.x;
    const int blank = CC - 1;

    const int*   lab  = y_true + b * LL;
    const float* base = y_pred + (size_t)b * TT * CC;

    int   col[4];
    float kup[4], kdn[4];
    #pragma unroll
    for (int i = 0; i < 4; ++i) {
        const int li = 4 * lane + i;
        const int z  = lab[li];
        col[i] = z;
        const int zm = (li >= 1) ? lab[li - 1] : -1;
        kup[i] = (z != zm) ? 1.0f : 0.0f;
        kdn[i] = (li <= 254 && lab[li + 1] != z) ? 1.0f : 0.0f;
    }

    float f[9];
    #pragma unroll
    for (int j = 0; j < 9; ++j) f[j] = 0.0f;
    int  e = 0;
    bool lzero;

    if (w == 0) {
        if (lane == 0) { f[0] = base[blank] + EPSF; f[1] = base[col[0]] + EPSF; }
        lzero = (lane != 0);
    } else {
        if (lane == 63) {
            const float* rT = base + (size_t)(TT - 1) * CC;
            f[7] = rT[col[3]] + EPSF; f[8] = rT[blank] + EPSF;
        }
        lzero = (lane != 63);
    }

    float pfb[DPTH]; float pfl[DPTH][4];
    #pragma unroll
    for (int k = 0; k < DPTH; ++k) {
        const int r = (w == 0) ? (1 + k) : (TT - 2 - k);
        const float* rp = base + (size_t)r * CC;
        pfb[k] = rp[blank];
        #pragma unroll
        for (int i = 0; i < 4; ++i) pfl[k][i] = rp[col[i]];
    }

    auto renorm = [&]() {
        float m = fmaxf(fmaxf(fmaxf(f[0], f[1]), fmaxf(f[2], f[3])),
                        fmaxf(fmaxf(f[4], f[5]), fmaxf(f[6], fmaxf(f[7], f[8]))));
        const int em = FREXP_EXP(m);
        #pragma unroll
        for (int j = 0; j < 9; ++j) f[j] = LDEXP(f[j], -em);
        e += em;
    };
    auto fwd_step = [&](float pb, float p0, float p1, float p2, float p3) {
        float u7 = __shfl_up(f[7], 1);
        int   ue = __shfl_up(e, 1);
        if (lane == 0) { u7 = 0.0f; ue = e; }
        int dlt = ue - e;
        const bool rb = lzero || (dlt >= RBTH);
        if (__ballot(rb)) {
            const int sh = rb ? -dlt : 0;
            #pragma unroll
            for (int j = 0; j < 9; ++j) f[j] = LDEXP(f[j], sh);
            e = rb ? ue : e; dlt = rb ? 0 : dlt;
            lzero = lzero && (u7 == 0.0f);
        }
        const float bf = LDEXP(u7, dlt);
        const float n0 = (f[0] + bf) * pb;
        const float n1 = (f[1] + f[0] + bf   * kup[0]) * p0;
        const float n2 = (f[2] + f[1]) * pb;
        const float n3 = (f[3] + f[2] + f[1] * kup[1]) * p1;
        const float n4 = (f[4] + f[3]) * pb;
        const float n5 = (f[5] + f[4] + f[3] * kup[2]) * p2;
        const float n6 = (f[6] + f[5]) * pb;
        const float n7 = (f[7] + f[6] + f[5] * kup[3]) * p3;
        const float n8 = (f[8] + f[7]) * pb;
        f[0]=n0; f[1]=n1; f[2]=n2; f[3]=n3; f[4]=n4;
        f[5]=n5; f[6]=n6; f[7]=n7; f[8]=n8;
    };
    auto bwd_step = [&](float pb, float p0, float p1, float p2, float p3) {
        float d1 = __shfl_down(f[1], 1);
        int   de = __shfl_down(e, 1);
        if (lane == 63) { d1 = 0.0f; de = e; }
        int dlt = de - e;
        const bool rb = lzero || (dlt >= RBTH);
        if (__ballot(rb)) {
            const int sh = rb ? -dlt : 0;
            #pragma unroll
            for (int j = 0; j < 9; ++j) f[j] = LDEXP(f[j], sh);
            e = rb ? de : e; dlt = rb ? 0 : dlt;
            lzero = lzero && (d1 == 0.0f);
        }
        const float bf = LDEXP(d1, dlt);
        const float n0 = (f[0] + f[1]) * pb;
        const float n1 = (f[1] + f[2] + f[3] * kdn[0]) * p0;
        const float n2 = (f[2] + f[3]) * pb;
        const float n3 = (f[3] + f[4] + f[5] * kdn[1]) * p1;
        const float n4 = (f[4] + f[5]) * pb;
        const float n5 = (f[5] + f[6] + f[7] * kdn[2]) * p2;
        const float n6 = (f[6] + f[7]) * pb;
        const float n7 = (f[7] + f[8] + bf   * kdn[3]) * p3;
        const float n8 = (f[8] + bf) * pb;
        f[0]=n0; f[1]=n1; f[2]=n2; f[3]=n3; f[4]=n4;
        f[5]=n5; f[6]=n6; f[7]=n7; f[8]=n8;
    };

    if (w == 0) {
        for (int c = 0; c < NCH; ++c) {
            #pragma unroll
            for (int k = 0; k < DPTH; ++k) {
                const float pb = pfb[k] + EPSF;
                const float p0 = pfl[k][0] + EPSF, p1 = pfl[k][1] + EPSF;
                const float p2 = pfl[k][2] + EPSF, p3 = pfl[k][3] + EPSF;
                int tp = 1 + c * DPTH + k + DPTH; if (tp > TM) tp = TM;
                const float* rp = base + (size_t)tp * CC;
                pfb[k] = rp[blank];
                #pragma unroll
                for (int i = 0; i < 4; ++i) pfl[k][i] = rp[col[i]];
                fwd_step(pb, p0, p1, p2, p3);
                if (k == 3 || k == 7) renorm();
            }
        }
        #pragma unroll
        for (int k = 0; k < 7; ++k) {
            fwd_step(pfb[k] + EPSF, pfl[k][0] + EPSF, pfl[k][1] + EPSF,
                     pfl[k][2] + EPSF, pfl[k][3] + EPSF);
            if (k == 3) renorm();
        }
    } else {
        for (int c = 0; c < NCH; ++c) {
            #pragma unroll
            for (int k = 0; k < DPTH; ++k) {
                const float pb = pfb[k] + EPSF;
                const float p0 = pfl[k][0] + EPSF, p1 = pfl[k][1] + EPSF;
                const float p2 = pfl[k][2] + EPSF, p3 = pfl[k][3] + EPSF;
                int tp = (TT - 2) - (c * DPTH + k) - DPTH; if (tp < TM + 1) tp = TM + 1;
                const float* rp = base + (size_t)tp * CC;
                pfb[k] = rp[blank];
                #pragma unroll
                for (int i = 0; i < 4; ++i) pfl[k][i] = rp[col[i]];
                bwd_step(pb, p0, p1, p2, p3);
                if (k == 3 || k == 7) renorm();
            }
        }
        #pragma unroll
        for (int k = 0; k < 7; ++k) {
            bwd_step(pfb[k] + EPSF, pfl[k][0] + EPSF, pfl[k][1] + EPSF,
                     pfl[k][2] + EPSF, pfl[k][3] + EPSF);
            if (k == 3) renorm();
        }

        float d1 = __shfl_down(f[1], 1);
        int   de = __shfl_down(e, 1);
        if (lane == 63) { d1 = 0.0f; de = e; }
        int dlt = de - e;
        if (dlt >= RBTH) {
            #pragma unroll
            for (int j = 0; j < 9; ++j) f[j] = LDEXP(f[j], -dlt);
            e = de; dlt = 0;
        }
        const float bf = LDEXP(d1, dlt);
        float cb[9];
        cb[0] = f[0] + f[1];
        cb[1] = f[1] + f[2] + f[3] * kdn[0];
        cb[2] = f[2] + f[3];
        cb[3] = f[3] + f[4] + f[5] * kdn[1];
        cb[4] = f[4] + f[5];
        cb[5] = f[5] + f[6] + f[7] * kdn[2];
        cb[6] = f[6] + f[7];
        cb[7] = f[7] + f[8] + bf   * kdn[3];
        cb[8] = f[8] + bf;
        #pragma unroll
        for (int j = 0; j < 8; ++j) cw[8 * lane + j] = cb[j];
        if (lane == 63) cw[512] = cb[8];
        ew[lane] = e;
    }

    __syncthreads();

    if (w == 0) {
        float part = 0.0f;
        #pragma unroll
        for (int j = 0; j < 8; ++j) part += f[j] * cw[8 * lane + j];
        if (lane == 63) part += f[8] * cw[512];
        int   ep = (part > 0.0f) ? (e + ew[lane]) : EMINI;
        float m  = part;
        #pragma unroll
        for (int d = 1; d < 64; d <<= 1) {
            const float mo = __shfl_xor(m, d);
            const int   eo = __shfl_xor(ep, d);
            const int   E  = ep > eo ? ep : eo;
            m  = LDEXP(m, ep - E) + LDEXP(mo, eo - E);
            ep = E;
        }
        if (lane == 0)
            out[b] = -LN2F * ((float)ep + __builtin_amdgcn_logf(m));
    }
}

extern "C" void kernel_launch(void* const* d_in, const int* in_sizes, int n_in,
                              void* d_out, int out_size, void* d_ws, size_t ws_size,
                              hipStream_t stream)
{
    const int*   y_true = (const int*)d_in[0];
    const float* y_pred = (const float*)d_in[1];
    float*       out    = (float*)d_out;
    const int B = in_sizes[0] / LL;   // 32

    const size_t need = (size_t)B * TT * GSTR * sizeof(float);  // ~68.2 MB
    if (ws_size >= need) {
        float* gat = (float*)d_ws;
        ctc_gather_kernel<<<dim3(B, 32), 256, 0, stream>>>(y_true, y_pred, gat);
        ctc_grp_kernel<<<B, 128, 0, stream>>>(y_true, y_pred, gat, out);
    } else {
        ctc_fb_kernel<<<B, 128, 0, stream>>>(y_true, y_pred, out);
    }
}